// Round 6
// baseline (158.622 us; speedup 1.0000x reference)
//
#include <hip/hip_runtime.h>
#include <hip/hip_bf16.h>

#define NNODES 50000
#define NEDGES 640000
#define HID 128

typedef __attribute__((ext_vector_type(8)))  short  short8;
typedef __attribute__((ext_vector_type(16))) float  f32x16;
typedef __attribute__((ext_vector_type(4)))  float  f32x4v;

static __device__ __forceinline__ short f2bf(float x) {
    return __builtin_bit_cast(short, __float2bfloat16(x));
}
static __device__ __forceinline__ float bf2f(unsigned short x) {
    unsigned int u = ((unsigned int)x) << 16;
    return __builtin_bit_cast(float, u);
}

// =====================================================================
// Kernel 1: pre[n][0:128] = h[n]*W1[0:128] + b1 ; pre[n][128:256] = h[n]*W1[128:256]
// Split into 2 col-half blocks: 32KB LDS, 64-VGPR acc, grid 782 (~3 blk/CU).
// =====================================================================
__global__ __launch_bounds__(256, 2)
void gemm_pre(const float* __restrict__ h,
              const float* __restrict__ W1,
              const float* __restrict__ b1,
              unsigned short* __restrict__ pre)
{
    __shared__ short8 w1s8[128 * 16];   // 32 KB: [col 0..127][k-chunk 0..15] swizzled
    short* w1s = (short*)w1s8;
    const int tid  = threadIdx.x;
    const int mblk = blockIdx.x >> 1;
    const int ch   = blockIdx.x & 1;    // 0: u-half (W1 rows 0..127 +b1), 1: v-half (rows 128..255)

    for (int idx = tid; idx < 128 * 128; idx += 256) {
        int k = idx >> 7, col = idx & 127;
        float val = W1[(ch * 128 + k) * HID + col];
        int c = (k >> 3) ^ (col & 7);
        w1s[col * 128 + c * 8 + (k & 7)] = f2bf(val);
    }
    __syncthreads();

    const int lane = tid & 63;
    const int wid  = tid >> 6;
    const int l31  = lane & 31;
    const int grp  = lane >> 5;

    const int mb = mblk * 128 + wid * 32;
    int arow = mb + l31;
    if (arow > NNODES - 1) arow = NNODES - 1;
    const float* ap = h + (size_t)arow * HID + grp * 8;

    f32x16 acc[4];
    #pragma unroll
    for (int nt = 0; nt < 4; ++nt)
        #pragma unroll
        for (int r = 0; r < 16; ++r) acc[nt][r] = 0.f;

    #pragma unroll
    for (int ks = 0; ks < 8; ++ks) {
        f32x4v a0 = *(const f32x4v*)(ap + ks * 16);
        f32x4v a1 = *(const f32x4v*)(ap + ks * 16 + 4);
        short8 af;
        af[0] = f2bf(a0.x); af[1] = f2bf(a0.y); af[2] = f2bf(a0.z); af[3] = f2bf(a0.w);
        af[4] = f2bf(a1.x); af[5] = f2bf(a1.y); af[6] = f2bf(a1.z); af[7] = f2bf(a1.w);
        #pragma unroll
        for (int nt = 0; nt < 4; ++nt) {
            const int col = nt * 32 + l31;
            short8 bf = w1s8[col * 16 + ((ks * 2 + grp) ^ (col & 7))];
            acc[nt] = __builtin_amdgcn_mfma_f32_32x32x16_bf16(af, bf, acc[nt], 0, 0, 0);
        }
    }

    float b1v[4];
    #pragma unroll
    for (int nt = 0; nt < 4; ++nt)
        b1v[nt] = ch ? 0.f : b1[nt * 32 + l31];

    #pragma unroll
    for (int r = 0; r < 16; ++r) {
        const int row = mb + ((r & 3) + 8 * (r >> 2) + 4 * grp);
        if (row < NNODES) {
            #pragma unroll
            for (int nt = 0; nt < 4; ++nt)
                pre[(size_t)row * 256 + ch * 128 + nt * 32 + l31] =
                    (unsigned short)f2bf(acc[nt][r] + b1v[nt]);
        }
    }
}

// =====================================================================
// Kernel 2: per-edge apply. 8 lanes per edge, 16 cols each.
// out[e] = relu(pre_u[u] + pre_v[v] + ea0*W1r256 + ea1*W1r257) . W2 + b2
// grid 2000 x 32 edges x 10 iters = 640000 exactly; 8 blocks/CU (full occ).
// =====================================================================
#define NBLK 2000
#define EPI  32
#define ESTRIDE (NBLK * EPI)

__global__ __launch_bounds__(256, 8)
void edge_apply(const unsigned short* __restrict__ pre,
                const int* __restrict__ ei,
                const float* __restrict__ ea,
                const float* __restrict__ W1,
                const float* __restrict__ W2,
                const float* __restrict__ b2,
                float* __restrict__ out)
{
    const int tid  = threadIdx.x;
    const int sub  = tid & 7;
    const int gid0 = blockIdx.x * EPI + (tid >> 3);

    float r256v[16], r257v[16], w2v[16];
    #pragma unroll
    for (int q = 0; q < 4; ++q) {
        f32x4v a = *(const f32x4v*)(W1 + 256 * HID + sub * 16 + q * 4);
        f32x4v b = *(const f32x4v*)(W1 + 257 * HID + sub * 16 + q * 4);
        f32x4v c = *(const f32x4v*)(W2 + sub * 16 + q * 4);
        r256v[q*4+0]=a.x; r256v[q*4+1]=a.y; r256v[q*4+2]=a.z; r256v[q*4+3]=a.w;
        r257v[q*4+0]=b.x; r257v[q*4+1]=b.y; r257v[q*4+2]=b.z; r257v[q*4+3]=b.w;
        w2v [q*4+0]=c.x; w2v [q*4+1]=c.y; w2v [q*4+2]=c.z; w2v [q*4+3]=c.w;
    }
    const float b2v = b2[0];

    const bool is64 = (ei[1] == 0) && (ei[3] == 0) && (ei[5] == 0) && (ei[7] == 0);
    const long long* ei64 = (const long long*)ei;

    int e = gid0;
    int u = 0, v = 0; float ea0 = 0.f, ea1 = 0.f;
    if (e < NEDGES) {
        u = is64 ? (int)ei64[e] : ei[e];
        v = is64 ? (int)ei64[NEDGES + e] : ei[NEDGES + e];
        ea0 = ea[2 * e]; ea1 = ea[2 * e + 1];
    }

    for (; e < NEDGES; e += ESTRIDE) {
        const int u_c = u, v_c = v;
        const float ea0_c = ea0, ea1_c = ea1;
        {
            const int en = e + ESTRIDE;
            if (en < NEDGES) {
                u = is64 ? (int)ei64[en] : ei[en];
                v = is64 ? (int)ei64[NEDGES + en] : ei[NEDGES + en];
                ea0 = ea[2 * en]; ea1 = ea[2 * en + 1];
            }
        }

        const unsigned short* pu = pre + (size_t)u_c * 256 + sub * 16;
        const unsigned short* pv = pre + (size_t)v_c * 256 + 128 + sub * 16;
        short8 g0 = *(const short8*)(pu);
        short8 g1 = *(const short8*)(pu + 8);
        short8 g2 = *(const short8*)(pv);
        short8 g3 = *(const short8*)(pv + 8);

        float s = 0.f;
        #pragma unroll
        for (int i = 0; i < 8; ++i) {
            float hid = bf2f((unsigned short)g0[i]) + bf2f((unsigned short)g2[i]);
            hid = fmaf(ea0_c, r256v[i], hid);
            hid = fmaf(ea1_c, r257v[i], hid);
            s = fmaf(fmaxf(hid, 0.f), w2v[i], s);
        }
        #pragma unroll
        for (int i = 0; i < 8; ++i) {
            float hid = bf2f((unsigned short)g1[i]) + bf2f((unsigned short)g3[i]);
            hid = fmaf(ea0_c, r256v[8 + i], hid);
            hid = fmaf(ea1_c, r257v[8 + i], hid);
            s = fmaf(fmaxf(hid, 0.f), w2v[8 + i], s);
        }

        s += __shfl_xor(s, 1, 64);
        s += __shfl_xor(s, 2, 64);
        s += __shfl_xor(s, 4, 64);
        if (sub == 0) out[e] = s + b2v;
    }
}

// =====================================================================
// Fallback (ws too small): monolithic f32-gather MFMA kernel
// =====================================================================
#define NWG 500
#define EPW 128

__global__ __launch_bounds__(256, 2)
void edgehead_mono(const float* __restrict__ h,
                   const int* __restrict__ ei,
                   const float* __restrict__ ea,
                   const float* __restrict__ W1,
                   const float* __restrict__ b1,
                   const float* __restrict__ W2,
                   const float* __restrict__ b2,
                   float* __restrict__ out)
{
    __shared__ short8 w1t8[128 * 32];
    __shared__ short8 w1e8[128 * 3];
    short* w1s  = (short*)w1t8;
    short* w1es = (short*)w1e8;
    const int tid = threadIdx.x;

    for (int idx = tid; idx < 256 * HID; idx += 256) {
        int k = idx >> 7, col = idx & 127;
        w1s[col * 256 + (k ^ ((col & 7) << 3))] = f2bf(W1[idx]);
    }
    if (tid < HID) {
        int col = tid, base = col * 24;
        w1es[base + 0] = f2bf(W1[256 * HID + col]);
        w1es[base + 1] = f2bf(W1[257 * HID + col]);
        w1es[base + 2] = f2bf(b1[col]);
        #pragma unroll
        for (int j = 3; j < 16; ++j) w1es[base + j] = 0;
    }
    __syncthreads();

    const int lane = tid & 63, wid = tid >> 6, l31 = lane & 31, grp = lane >> 5;
    const bool is64 = (ei[1] == 0) && (ei[3] == 0) && (ei[5] == 0) && (ei[7] == 0);
    const long long* ei64 = (const long long*)ei;

    float w2v[4];
    #pragma unroll
    for (int nt = 0; nt < 4; ++nt) w2v[nt] = W2[nt * 32 + l31];
    const float b2v = b2[0];

    for (int ebase = blockIdx.x * EPW + wid * 32; ebase < NEDGES; ebase += NWG * EPW) {
        const int e = ebase + l31;
        const int u = is64 ? (int)ei64[e] : ei[e];
        const int v = is64 ? (int)ei64[NEDGES + e] : ei[NEDGES + e];
        const float ea0 = ea[2 * e], ea1 = ea[2 * e + 1];
        const float* pu32 = h + (size_t)u * HID + grp * 8;
        const float* pv32 = h + (size_t)v * HID + grp * 8;

        f32x16 acc[4];
        #pragma unroll
        for (int nt = 0; nt < 4; ++nt)
            #pragma unroll
            for (int r = 0; r < 16; ++r) acc[nt][r] = 0.f;

        #pragma unroll
        for (int ks = 0; ks < 17; ++ks) {
            short8 af;
            if (ks < 16) {
                const float* p = (ks < 8) ? (pu32 + ks * 16) : (pv32 + (ks - 8) * 16);
                f32x4v a0 = *(const f32x4v*)(p);
                f32x4v a1 = *(const f32x4v*)(p + 4);
                af[0]=f2bf(a0.x); af[1]=f2bf(a0.y); af[2]=f2bf(a0.z); af[3]=f2bf(a0.w);
                af[4]=f2bf(a1.x); af[5]=f2bf(a1.y); af[6]=f2bf(a1.z); af[7]=f2bf(a1.w);
            } else {
                af[0] = grp ? (short)0 : f2bf(ea0);
                af[1] = grp ? (short)0 : f2bf(ea1);
                af[2] = grp ? (short)0 : (short)0x3F80;
                af[3]=0; af[4]=0; af[5]=0; af[6]=0; af[7]=0;
            }
            #pragma unroll
            for (int nt = 0; nt < 4; ++nt) {
                const int col = nt * 32 + l31;
                short8 bf = (ks < 16)
                    ? w1t8[col * 32 + ((ks * 2 + grp) ^ (l31 & 7))]
                    : w1e8[col * 3 + grp];
                acc[nt] = __builtin_amdgcn_mfma_f32_32x32x16_bf16(af, bf, acc[nt], 0, 0, 0);
            }
        }

        float pr[16];
        #pragma unroll
        for (int r = 0; r < 16; ++r) {
            float s = fmaxf(acc[0][r], 0.f) * w2v[0];
            s = fmaf(fmaxf(acc[1][r], 0.f), w2v[1], s);
            s = fmaf(fmaxf(acc[2][r], 0.f), w2v[2], s);
            s = fmaf(fmaxf(acc[3][r], 0.f), w2v[3], s);
            pr[r] = s;
        }
        #define FOLD(MASK, A, B) { \
            const bool hi = (lane & MASK) != 0; \
            float snd = hi ? pr[A] : pr[B]; \
            float kp  = hi ? pr[B] : pr[A]; \
            pr[A] = kp + __shfl_xor(snd, MASK, 64); }
        #pragma unroll
        for (int i = 0; i < 8; ++i) FOLD(1, i, i + 8)
        #pragma unroll
        for (int i = 0; i < 4; ++i) FOLD(2, i, i + 4)
        #pragma unroll
        for (int i = 0; i < 2; ++i) FOLD(4, i, i + 2)
        FOLD(8, 0, 1)
        #undef FOLD
        float val = pr[0] + __shfl_xor(pr[0], 16, 64);
        const int reff = ((lane & 1) << 3) | ((lane & 2) << 1) | ((lane & 4) >> 1) | ((lane & 8) >> 3);
        const int row  = (reff & 3) + ((reff >> 2) << 3) + grp * 4;
        if ((lane & 16) == 0) out[ebase + row] = val + b2v;
    }
}

extern "C" void kernel_launch(void* const* d_in, const int* in_sizes, int n_in,
                              void* d_out, int out_size, void* d_ws, size_t ws_size,
                              hipStream_t stream) {
    const float* h  = (const float*)d_in[0];
    const int*   ei = (const int*)d_in[1];
    const float* ea = (const float*)d_in[2];
    const float* W1 = (const float*)d_in[3];
    const float* b1 = (const float*)d_in[4];
    const float* W2 = (const float*)d_in[5];
    const float* b2 = (const float*)d_in[6];
    float* out = (float*)d_out;

    const size_t need = (size_t)NNODES * 256 * sizeof(unsigned short);  // 25.6 MB
    if (ws_size >= need) {
        unsigned short* pre = (unsigned short*)d_ws;
        const int mblocks = ((NNODES + 127) / 128) * 2;   // 782
        hipLaunchKernelGGL(gemm_pre, dim3(mblocks), dim3(256), 0, stream, h, W1, b1, pre);
        hipLaunchKernelGGL(edge_apply, dim3(NBLK), dim3(256), 0, stream,
                           pre, ei, ea, W1, W2, b2, out);
    } else {
        hipLaunchKernelGGL(edgehead_mono, dim3(NWG), dim3(256), 0, stream,
                           h, ei, ea, W1, b1, W2, b2, out);
    }
}

// Round 7
// 68.828 us; speedup vs baseline: 2.3046x; 2.3046x over previous
//
#include <hip/hip_runtime.h>
#include <hip/hip_bf16.h>

#define NNODES 50000
#define NEDGES 640000
#define HID 128

typedef __attribute__((ext_vector_type(8)))  short  short8;
typedef __attribute__((ext_vector_type(16))) float  f32x16;
typedef __attribute__((ext_vector_type(4)))  float  f32x4v;

static __device__ __forceinline__ short f2bf(float x) {
    return __builtin_bit_cast(short, __float2bfloat16(x));
}
static __device__ __forceinline__ float bf2f(unsigned short x) {
    unsigned int u = ((unsigned int)x) << 16;
    return __builtin_bit_cast(float, u);
}

// =====================================================================
// Kernel 1: pre[n][0:128] = h[n]*W1[0:128] + b1 ; pre[n][128:256] = h[n]*W1[128:256]
// Split into 2 col-half blocks: 32KB LDS, 64-VGPR acc, grid 782 (~3 blk/CU).
// Measured ~15us in R6 — keep unchanged.
// =====================================================================
__global__ __launch_bounds__(256, 2)
void gemm_pre(const float* __restrict__ h,
              const float* __restrict__ W1,
              const float* __restrict__ b1,
              unsigned short* __restrict__ pre)
{
    __shared__ short8 w1s8[128 * 16];   // 32 KB: [col 0..127][k-chunk 0..15] swizzled
    short* w1s = (short*)w1s8;
    const int tid  = threadIdx.x;
    const int mblk = blockIdx.x >> 1;
    const int ch   = blockIdx.x & 1;    // 0: u-half (W1 rows 0..127 +b1), 1: v-half (rows 128..255)

    for (int idx = tid; idx < 128 * 128; idx += 256) {
        int k = idx >> 7, col = idx & 127;
        float val = W1[(ch * 128 + k) * HID + col];
        int c = (k >> 3) ^ (col & 7);
        w1s[col * 128 + c * 8 + (k & 7)] = f2bf(val);
    }
    __syncthreads();

    const int lane = tid & 63;
    const int wid  = tid >> 6;
    const int l31  = lane & 31;
    const int grp  = lane >> 5;

    const int mb = mblk * 128 + wid * 32;
    int arow = mb + l31;
    if (arow > NNODES - 1) arow = NNODES - 1;
    const float* ap = h + (size_t)arow * HID + grp * 8;

    f32x16 acc[4];
    #pragma unroll
    for (int nt = 0; nt < 4; ++nt)
        #pragma unroll
        for (int r = 0; r < 16; ++r) acc[nt][r] = 0.f;

    #pragma unroll
    for (int ks = 0; ks < 8; ++ks) {
        f32x4v a0 = *(const f32x4v*)(ap + ks * 16);
        f32x4v a1 = *(const f32x4v*)(ap + ks * 16 + 4);
        short8 af;
        af[0] = f2bf(a0.x); af[1] = f2bf(a0.y); af[2] = f2bf(a0.z); af[3] = f2bf(a0.w);
        af[4] = f2bf(a1.x); af[5] = f2bf(a1.y); af[6] = f2bf(a1.z); af[7] = f2bf(a1.w);
        #pragma unroll
        for (int nt = 0; nt < 4; ++nt) {
            const int col = nt * 32 + l31;
            short8 bf = w1s8[col * 16 + ((ks * 2 + grp) ^ (col & 7))];
            acc[nt] = __builtin_amdgcn_mfma_f32_32x32x16_bf16(af, bf, acc[nt], 0, 0, 0);
        }
    }

    float b1v[4];
    #pragma unroll
    for (int nt = 0; nt < 4; ++nt)
        b1v[nt] = ch ? 0.f : b1[nt * 32 + l31];

    #pragma unroll
    for (int r = 0; r < 16; ++r) {
        const int row = mb + ((r & 3) + 8 * (r >> 2) + 4 * grp);
        if (row < NNODES) {
            #pragma unroll
            for (int nt = 0; nt < 4; ++nt)
                pre[(size_t)row * 256 + ch * 128 + nt * 32 + l31] =
                    (unsigned short)f2bf(acc[nt][r] + b1v[nt]);
        }
    }
}

// =====================================================================
// Kernel 2: per-edge apply. 8 lanes per edge, 16 cols each.
// R4-proven config: __launch_bounds__(256,4) -> VGPR 48, NO spill.
// (256,8) regressed: VGPR forced to 32, constants spilled, FETCH 3x. Do
// not raise min-waves here — the gather pipe is BW-pinned at ~3 TB/s.
// =====================================================================
#define NBLK 2000
#define EPI  32
#define ESTRIDE (NBLK * EPI)

__global__ __launch_bounds__(256, 4)
void edge_apply(const unsigned short* __restrict__ pre,
                const int* __restrict__ ei,
                const float* __restrict__ ea,
                const float* __restrict__ W1,
                const float* __restrict__ W2,
                const float* __restrict__ b2,
                float* __restrict__ out)
{
    const int tid  = threadIdx.x;
    const int sub  = tid & 7;
    const int gid0 = blockIdx.x * EPI + (tid >> 3);

    float r256v[16], r257v[16], w2v[16];
    #pragma unroll
    for (int q = 0; q < 4; ++q) {
        f32x4v a = *(const f32x4v*)(W1 + 256 * HID + sub * 16 + q * 4);
        f32x4v b = *(const f32x4v*)(W1 + 257 * HID + sub * 16 + q * 4);
        f32x4v c = *(const f32x4v*)(W2 + sub * 16 + q * 4);
        r256v[q*4+0]=a.x; r256v[q*4+1]=a.y; r256v[q*4+2]=a.z; r256v[q*4+3]=a.w;
        r257v[q*4+0]=b.x; r257v[q*4+1]=b.y; r257v[q*4+2]=b.z; r257v[q*4+3]=b.w;
        w2v [q*4+0]=c.x; w2v [q*4+1]=c.y; w2v [q*4+2]=c.z; w2v [q*4+3]=c.w;
    }
    const float b2v = b2[0];

    const bool is64 = (ei[1] == 0) && (ei[3] == 0) && (ei[5] == 0) && (ei[7] == 0);
    const long long* ei64 = (const long long*)ei;

    int e = gid0;
    int u = 0, v = 0; float ea0 = 0.f, ea1 = 0.f;
    if (e < NEDGES) {
        u = is64 ? (int)ei64[e] : ei[e];
        v = is64 ? (int)ei64[NEDGES + e] : ei[NEDGES + e];
        ea0 = ea[2 * e]; ea1 = ea[2 * e + 1];
    }

    for (; e < NEDGES; e += ESTRIDE) {
        const int u_c = u, v_c = v;
        const float ea0_c = ea0, ea1_c = ea1;
        {
            const int en = e + ESTRIDE;
            if (en < NEDGES) {
                u = is64 ? (int)ei64[en] : ei[en];
                v = is64 ? (int)ei64[NEDGES + en] : ei[NEDGES + en];
                ea0 = ea[2 * en]; ea1 = ea[2 * en + 1];
            }
        }

        const unsigned short* pu = pre + (size_t)u_c * 256 + sub * 16;
        const unsigned short* pv = pre + (size_t)v_c * 256 + 128 + sub * 16;
        short8 g0 = *(const short8*)(pu);
        short8 g1 = *(const short8*)(pu + 8);
        short8 g2 = *(const short8*)(pv);
        short8 g3 = *(const short8*)(pv + 8);

        float s = 0.f;
        #pragma unroll
        for (int i = 0; i < 8; ++i) {
            float hid = bf2f((unsigned short)g0[i]) + bf2f((unsigned short)g2[i]);
            hid = fmaf(ea0_c, r256v[i], hid);
            hid = fmaf(ea1_c, r257v[i], hid);
            s = fmaf(fmaxf(hid, 0.f), w2v[i], s);
        }
        #pragma unroll
        for (int i = 0; i < 8; ++i) {
            float hid = bf2f((unsigned short)g1[i]) + bf2f((unsigned short)g3[i]);
            hid = fmaf(ea0_c, r256v[8 + i], hid);
            hid = fmaf(ea1_c, r257v[8 + i], hid);
            s = fmaf(fmaxf(hid, 0.f), w2v[8 + i], s);
        }

        s += __shfl_xor(s, 1, 64);
        s += __shfl_xor(s, 2, 64);
        s += __shfl_xor(s, 4, 64);
        if (sub == 0) out[e] = s + b2v;
    }
}

// =====================================================================
// Fallback (ws too small): monolithic f32-gather MFMA kernel
// =====================================================================
#define NWG 500
#define EPW 128

__global__ __launch_bounds__(256, 2)
void edgehead_mono(const float* __restrict__ h,
                   const int* __restrict__ ei,
                   const float* __restrict__ ea,
                   const float* __restrict__ W1,
                   const float* __restrict__ b1,
                   const float* __restrict__ W2,
                   const float* __restrict__ b2,
                   float* __restrict__ out)
{
    __shared__ short8 w1t8[128 * 32];
    __shared__ short8 w1e8[128 * 3];
    short* w1s  = (short*)w1t8;
    short* w1es = (short*)w1e8;
    const int tid = threadIdx.x;

    for (int idx = tid; idx < 256 * HID; idx += 256) {
        int k = idx >> 7, col = idx & 127;
        w1s[col * 256 + (k ^ ((col & 7) << 3))] = f2bf(W1[idx]);
    }
    if (tid < HID) {
        int col = tid, base = col * 24;
        w1es[base + 0] = f2bf(W1[256 * HID + col]);
        w1es[base + 1] = f2bf(W1[257 * HID + col]);
        w1es[base + 2] = f2bf(b1[col]);
        #pragma unroll
        for (int j = 3; j < 16; ++j) w1es[base + j] = 0;
    }
    __syncthreads();

    const int lane = tid & 63, wid = tid >> 6, l31 = lane & 31, grp = lane >> 5;
    const bool is64 = (ei[1] == 0) && (ei[3] == 0) && (ei[5] == 0) && (ei[7] == 0);
    const long long* ei64 = (const long long*)ei;

    float w2v[4];
    #pragma unroll
    for (int nt = 0; nt < 4; ++nt) w2v[nt] = W2[nt * 32 + l31];
    const float b2v = b2[0];

    for (int ebase = blockIdx.x * EPW + wid * 32; ebase < NEDGES; ebase += NWG * EPW) {
        const int e = ebase + l31;
        const int u = is64 ? (int)ei64[e] : ei[e];
        const int v = is64 ? (int)ei64[NEDGES + e] : ei[NEDGES + e];
        const float ea0 = ea[2 * e], ea1 = ea[2 * e + 1];
        const float* pu32 = h + (size_t)u * HID + grp * 8;
        const float* pv32 = h + (size_t)v * HID + grp * 8;

        f32x16 acc[4];
        #pragma unroll
        for (int nt = 0; nt < 4; ++nt)
            #pragma unroll
            for (int r = 0; r < 16; ++r) acc[nt][r] = 0.f;

        #pragma unroll
        for (int ks = 0; ks < 17; ++ks) {
            short8 af;
            if (ks < 16) {
                const float* p = (ks < 8) ? (pu32 + ks * 16) : (pv32 + (ks - 8) * 16);
                f32x4v a0 = *(const f32x4v*)(p);
                f32x4v a1 = *(const f32x4v*)(p + 4);
                af[0]=f2bf(a0.x); af[1]=f2bf(a0.y); af[2]=f2bf(a0.z); af[3]=f2bf(a0.w);
                af[4]=f2bf(a1.x); af[5]=f2bf(a1.y); af[6]=f2bf(a1.z); af[7]=f2bf(a1.w);
            } else {
                af[0] = grp ? (short)0 : f2bf(ea0);
                af[1] = grp ? (short)0 : f2bf(ea1);
                af[2] = grp ? (short)0 : (short)0x3F80;
                af[3]=0; af[4]=0; af[5]=0; af[6]=0; af[7]=0;
            }
            #pragma unroll
            for (int nt = 0; nt < 4; ++nt) {
                const int col = nt * 32 + l31;
                short8 bf = (ks < 16)
                    ? w1t8[col * 32 + ((ks * 2 + grp) ^ (l31 & 7))]
                    : w1e8[col * 3 + grp];
                acc[nt] = __builtin_amdgcn_mfma_f32_32x32x16_bf16(af, bf, acc[nt], 0, 0, 0);
            }
        }

        float pr[16];
        #pragma unroll
        for (int r = 0; r < 16; ++r) {
            float s = fmaxf(acc[0][r], 0.f) * w2v[0];
            s = fmaf(fmaxf(acc[1][r], 0.f), w2v[1], s);
            s = fmaf(fmaxf(acc[2][r], 0.f), w2v[2], s);
            s = fmaf(fmaxf(acc[3][r], 0.f), w2v[3], s);
            pr[r] = s;
        }
        #define FOLD(MASK, A, B) { \
            const bool hi = (lane & MASK) != 0; \
            float snd = hi ? pr[A] : pr[B]; \
            float kp  = hi ? pr[B] : pr[A]; \
            pr[A] = kp + __shfl_xor(snd, MASK, 64); }
        #pragma unroll
        for (int i = 0; i < 8; ++i) FOLD(1, i, i + 8)
        #pragma unroll
        for (int i = 0; i < 4; ++i) FOLD(2, i, i + 4)
        #pragma unroll
        for (int i = 0; i < 2; ++i) FOLD(4, i, i + 2)
        FOLD(8, 0, 1)
        #undef FOLD
        float val = pr[0] + __shfl_xor(pr[0], 16, 64);
        const int reff = ((lane & 1) << 3) | ((lane & 2) << 1) | ((lane & 4) >> 1) | ((lane & 8) >> 3);
        const int row  = (reff & 3) + ((reff >> 2) << 3) + grp * 4;
        if ((lane & 16) == 0) out[ebase + row] = val + b2v;
    }
}

extern "C" void kernel_launch(void* const* d_in, const int* in_sizes, int n_in,
                              void* d_out, int out_size, void* d_ws, size_t ws_size,
                              hipStream_t stream) {
    const float* h  = (const float*)d_in[0];
    const int*   ei = (const int*)d_in[1];
    const float* ea = (const float*)d_in[2];
    const float* W1 = (const float*)d_in[3];
    const float* b1 = (const float*)d_in[4];
    const float* W2 = (const float*)d_in[5];
    const float* b2 = (const float*)d_in[6];
    float* out = (float*)d_out;

    const size_t need = (size_t)NNODES * 256 * sizeof(unsigned short);  // 25.6 MB
    if (ws_size >= need) {
        unsigned short* pre = (unsigned short*)d_ws;
        const int mblocks = ((NNODES + 127) / 128) * 2;   // 782
        hipLaunchKernelGGL(gemm_pre, dim3(mblocks), dim3(256), 0, stream, h, W1, b1, pre);
        hipLaunchKernelGGL(edge_apply, dim3(NBLK), dim3(256), 0, stream,
                           pre, ei, ea, W1, W2, b2, out);
    } else {
        hipLaunchKernelGGL(edgehead_mono, dim3(NWG), dim3(256), 0, stream,
                           h, ei, ea, W1, b1, W2, b2, out);
    }
}

// Round 8
// 52.952 us; speedup vs baseline: 2.9956x; 1.2998x over previous
//
#include <hip/hip_runtime.h>
#include <hip/hip_bf16.h>

#define NNODES 50000
#define NEDGES 640000
#define HID 128

typedef __attribute__((ext_vector_type(8)))  short  short8;
typedef __attribute__((ext_vector_type(16))) float  f32x16;
typedef __attribute__((ext_vector_type(4)))  float  f32x4v;
typedef __attribute__((ext_vector_type(4)))  unsigned int u32x4;

static __device__ __forceinline__ short f2bf(float x) {
    return __builtin_bit_cast(short, __float2bfloat16(x));
}

// =====================================================================
// Kernel 1: pre = [h*W1u + b1 | h*W1v], quantized to uint8 (bias 128)
// with per-(node,half) scale = rowmax/127 (f32, separate arrays).
// 2 col-half blocks: 32KB LDS, grid 782.
// =====================================================================
__global__ __launch_bounds__(256, 2)
void gemm_pre(const float* __restrict__ h,
              const float* __restrict__ W1,
              const float* __restrict__ b1,
              unsigned char* __restrict__ pre8,
              float* __restrict__ sU,
              float* __restrict__ sV)
{
    __shared__ short8 w1s8[128 * 16];   // 32 KB swizzled
    short* w1s = (short*)w1s8;
    const int tid  = threadIdx.x;
    const int mblk = blockIdx.x >> 1;
    const int ch   = blockIdx.x & 1;    // 0: u-half (+b1), 1: v-half

    for (int idx = tid; idx < 128 * 128; idx += 256) {
        int k = idx >> 7, col = idx & 127;
        float val = W1[(ch * 128 + k) * HID + col];
        int c = (k >> 3) ^ (col & 7);
        w1s[col * 128 + c * 8 + (k & 7)] = f2bf(val);
    }
    __syncthreads();

    const int lane = tid & 63;
    const int wid  = tid >> 6;
    const int l31  = lane & 31;
    const int grp  = lane >> 5;

    const int mb = mblk * 128 + wid * 32;
    int arow = mb + l31;
    if (arow > NNODES - 1) arow = NNODES - 1;
    const float* ap = h + (size_t)arow * HID + grp * 8;

    f32x16 acc[4];
    #pragma unroll
    for (int nt = 0; nt < 4; ++nt)
        #pragma unroll
        for (int r = 0; r < 16; ++r) acc[nt][r] = 0.f;

    #pragma unroll
    for (int ks = 0; ks < 8; ++ks) {
        f32x4v a0 = *(const f32x4v*)(ap + ks * 16);
        f32x4v a1 = *(const f32x4v*)(ap + ks * 16 + 4);
        short8 af;
        af[0] = f2bf(a0.x); af[1] = f2bf(a0.y); af[2] = f2bf(a0.z); af[3] = f2bf(a0.w);
        af[4] = f2bf(a1.x); af[5] = f2bf(a1.y); af[6] = f2bf(a1.z); af[7] = f2bf(a1.w);
        #pragma unroll
        for (int nt = 0; nt < 4; ++nt) {
            const int col = nt * 32 + l31;
            short8 bf = w1s8[col * 16 + ((ks * 2 + grp) ^ (col & 7))];
            acc[nt] = __builtin_amdgcn_mfma_f32_32x32x16_bf16(af, bf, acc[nt], 0, 0, 0);
        }
    }

    float b1v[4];
    #pragma unroll
    for (int nt = 0; nt < 4; ++nt)
        b1v[nt] = ch ? 0.f : b1[nt * 32 + l31];

    // epilogue: add bias, per-row absmax (cols are l31 x nt), quantize
    #pragma unroll
    for (int r = 0; r < 16; ++r) {
        float m = 0.f;
        #pragma unroll
        for (int nt = 0; nt < 4; ++nt) {
            float val = acc[nt][r] + b1v[nt];
            acc[nt][r] = val;
            m = fmaxf(m, fabsf(val));
        }
        m = fmaxf(m, __shfl_xor(m, 1, 64));
        m = fmaxf(m, __shfl_xor(m, 2, 64));
        m = fmaxf(m, __shfl_xor(m, 4, 64));
        m = fmaxf(m, __shfl_xor(m, 8, 64));
        m = fmaxf(m, __shfl_xor(m, 16, 64));

        const int row = mb + ((r & 3) + 8 * (r >> 2) + 4 * grp);
        if (row < NNODES) {
            const float inv = (m > 0.f) ? (127.f / m) : 0.f;
            if (l31 == 0) (ch ? sV : sU)[row] = m * (1.f / 127.f);
            #pragma unroll
            for (int nt = 0; nt < 4; ++nt) {
                int q = (int)rintf(acc[nt][r] * inv) + 128;
                pre8[(size_t)row * 256 + ch * 128 + nt * 32 + l31] = (unsigned char)q;
            }
        }
    }
}

// =====================================================================
// Kernel 2: per-edge apply on int8 pre. 8 lanes/edge, 16 cols each.
// 3-deep pipeline: idx[i+2] / scale+gather[i+1] / compute[i].
// exact 10 iters per thread (2000 blk x 32 edges x 10 = 640000).
// =====================================================================
#define NBLK 2000
#define EPI  32
#define ESTRIDE (NBLK * EPI)
#define NITER 10

__global__ __launch_bounds__(256, 4)
void edge_apply(const unsigned char* __restrict__ pre8,
                const float* __restrict__ sU,
                const float* __restrict__ sV,
                const int* __restrict__ ei,
                const float* __restrict__ ea,
                const float* __restrict__ W1,
                const float* __restrict__ W2,
                const float* __restrict__ b2,
                float* __restrict__ out)
{
    const int tid = threadIdx.x;
    const int sub = tid & 7;
    const int e0  = blockIdx.x * EPI + (tid >> 3);

    float r256v[16], r257v[16], w2v[16];
    #pragma unroll
    for (int q = 0; q < 4; ++q) {
        f32x4v a = *(const f32x4v*)(W1 + 256 * HID + sub * 16 + q * 4);
        f32x4v b = *(const f32x4v*)(W1 + 257 * HID + sub * 16 + q * 4);
        f32x4v c = *(const f32x4v*)(W2 + sub * 16 + q * 4);
        r256v[q*4+0]=a.x; r256v[q*4+1]=a.y; r256v[q*4+2]=a.z; r256v[q*4+3]=a.w;
        r257v[q*4+0]=b.x; r257v[q*4+1]=b.y; r257v[q*4+2]=b.z; r257v[q*4+3]=b.w;
        w2v [q*4+0]=c.x; w2v [q*4+1]=c.y; w2v [q*4+2]=c.z; w2v [q*4+3]=c.w;
    }
    const float b2v = b2[0];

    const bool is64 = (ei[1] == 0) && (ei[3] == 0) && (ei[5] == 0) && (ei[7] == 0);
    const long long* ei64 = (const long long*)ei;

    int   uu[3], vv[3];
    float a0v[3], a1v[3];
    float su[2], sv[2];
    u32x4 gu[2], gv[2];

    #pragma unroll
    for (int p = 0; p < 2; ++p) {
        const int ee = e0 + p * ESTRIDE;
        uu[p]  = is64 ? (int)ei64[ee] : ei[ee];
        vv[p]  = is64 ? (int)ei64[NEDGES + ee] : ei[NEDGES + ee];
        a0v[p] = ea[2 * ee]; a1v[p] = ea[2 * ee + 1];
    }
    su[0] = sU[uu[0]]; sv[0] = sV[vv[0]];
    gu[0] = *(const u32x4*)(pre8 + (size_t)uu[0] * 256 + sub * 16);
    gv[0] = *(const u32x4*)(pre8 + (size_t)vv[0] * 256 + 128 + sub * 16);

    #pragma unroll
    for (int i = 0; i < NITER; ++i) {
        const int cur = i % 3, nxt = (i + 1) % 3, nx2 = (i + 2) % 3;
        const int cb = i & 1, nb = (i + 1) & 1;

        // prefetch idx bundle i+2 (clamped to a valid edge; unused at tail)
        {
            const int ee = (i + 2 < NITER) ? (e0 + (i + 2) * ESTRIDE) : e0;
            uu[nx2]  = is64 ? (int)ei64[ee] : ei[ee];
            vv[nx2]  = is64 ? (int)ei64[NEDGES + ee] : ei[NEDGES + ee];
            a0v[nx2] = ea[2 * ee]; a1v[nx2] = ea[2 * ee + 1];
        }
        // prefetch scales + gather for i+1
        su[nb] = sU[uu[nxt]]; sv[nb] = sV[vv[nxt]];
        gu[nb] = *(const u32x4*)(pre8 + (size_t)uu[nxt] * 256 + sub * 16);
        gv[nb] = *(const u32x4*)(pre8 + (size_t)vv[nxt] * 256 + 128 + sub * 16);

        // compute iteration i
        const float s_u = su[cb], s_v = sv[cb];
        const float K  = -128.f * (s_u + s_v);
        const float a0 = a0v[cur], a1 = a1v[cur];
        float s = 0.f;
        #pragma unroll
        for (int dw = 0; dw < 4; ++dw) {
            const unsigned pu = gu[cb][dw];
            const unsigned pv = gv[cb][dw];
            #pragma unroll
            for (int b = 0; b < 4; ++b) {
                const int j = dw * 4 + b;
                const float fu = (float)((pu >> (8 * b)) & 0xffu);  // v_cvt_f32_ubyteN
                const float fv = (float)((pv >> (8 * b)) & 0xffu);
                float bK  = fmaf(a0, r256v[j], fmaf(a1, r257v[j], K));
                float hid = fmaf(s_u, fu, fmaf(s_v, fv, bK));
                s = fmaf(fmaxf(hid, 0.f), w2v[j], s);
            }
        }

        s += __shfl_xor(s, 1, 64);
        s += __shfl_xor(s, 2, 64);
        s += __shfl_xor(s, 4, 64);
        if (sub == 0) out[e0 + i * ESTRIDE] = s + b2v;
    }
}

// =====================================================================
// Fallback (ws too small): monolithic f32-gather MFMA kernel
// =====================================================================
#define NWG 500
#define EPW 128

__global__ __launch_bounds__(256, 2)
void edgehead_mono(const float* __restrict__ h,
                   const int* __restrict__ ei,
                   const float* __restrict__ ea,
                   const float* __restrict__ W1,
                   const float* __restrict__ b1,
                   const float* __restrict__ W2,
                   const float* __restrict__ b2,
                   float* __restrict__ out)
{
    __shared__ short8 w1t8[128 * 32];
    __shared__ short8 w1e8[128 * 3];
    short* w1s  = (short*)w1t8;
    short* w1es = (short*)w1e8;
    const int tid = threadIdx.x;

    for (int idx = tid; idx < 256 * HID; idx += 256) {
        int k = idx >> 7, col = idx & 127;
        w1s[col * 256 + (k ^ ((col & 7) << 3))] = f2bf(W1[idx]);
    }
    if (tid < HID) {
        int col = tid, base = col * 24;
        w1es[base + 0] = f2bf(W1[256 * HID + col]);
        w1es[base + 1] = f2bf(W1[257 * HID + col]);
        w1es[base + 2] = f2bf(b1[col]);
        #pragma unroll
        for (int j = 3; j < 16; ++j) w1es[base + j] = 0;
    }
    __syncthreads();

    const int lane = tid & 63, wid = tid >> 6, l31 = lane & 31, grp = lane >> 5;
    const bool is64 = (ei[1] == 0) && (ei[3] == 0) && (ei[5] == 0) && (ei[7] == 0);
    const long long* ei64 = (const long long*)ei;

    float w2v[4];
    #pragma unroll
    for (int nt = 0; nt < 4; ++nt) w2v[nt] = W2[nt * 32 + l31];
    const float b2v = b2[0];

    for (int ebase = blockIdx.x * EPW + wid * 32; ebase < NEDGES; ebase += NWG * EPW) {
        const int e = ebase + l31;
        const int u = is64 ? (int)ei64[e] : ei[e];
        const int v = is64 ? (int)ei64[NEDGES + e] : ei[NEDGES + e];
        const float ea0 = ea[2 * e], ea1 = ea[2 * e + 1];
        const float* pu32 = h + (size_t)u * HID + grp * 8;
        const float* pv32 = h + (size_t)v * HID + grp * 8;

        f32x16 acc[4];
        #pragma unroll
        for (int nt = 0; nt < 4; ++nt)
            #pragma unroll
            for (int r = 0; r < 16; ++r) acc[nt][r] = 0.f;

        #pragma unroll
        for (int ks = 0; ks < 17; ++ks) {
            short8 af;
            if (ks < 16) {
                const float* p = (ks < 8) ? (pu32 + ks * 16) : (pv32 + (ks - 8) * 16);
                f32x4v a0 = *(const f32x4v*)(p);
                f32x4v a1 = *(const f32x4v*)(p + 4);
                af[0]=f2bf(a0.x); af[1]=f2bf(a0.y); af[2]=f2bf(a0.z); af[3]=f2bf(a0.w);
                af[4]=f2bf(a1.x); af[5]=f2bf(a1.y); af[6]=f2bf(a1.z); af[7]=f2bf(a1.w);
            } else {
                af[0] = grp ? (short)0 : f2bf(ea0);
                af[1] = grp ? (short)0 : f2bf(ea1);
                af[2] = grp ? (short)0 : (short)0x3F80;
                af[3]=0; af[4]=0; af[5]=0; af[6]=0; af[7]=0;
            }
            #pragma unroll
            for (int nt = 0; nt < 4; ++nt) {
                const int col = nt * 32 + l31;
                short8 bf = (ks < 16)
                    ? w1t8[col * 32 + ((ks * 2 + grp) ^ (l31 & 7))]
                    : w1e8[col * 3 + grp];
                acc[nt] = __builtin_amdgcn_mfma_f32_32x32x16_bf16(af, bf, acc[nt], 0, 0, 0);
            }
        }

        float pr[16];
        #pragma unroll
        for (int r = 0; r < 16; ++r) {
            float s = fmaxf(acc[0][r], 0.f) * w2v[0];
            s = fmaf(fmaxf(acc[1][r], 0.f), w2v[1], s);
            s = fmaf(fmaxf(acc[2][r], 0.f), w2v[2], s);
            s = fmaf(fmaxf(acc[3][r], 0.f), w2v[3], s);
            pr[r] = s;
        }
        #define FOLD(MASK, A, B) { \
            const bool hi = (lane & MASK) != 0; \
            float snd = hi ? pr[A] : pr[B]; \
            float kp  = hi ? pr[B] : pr[A]; \
            pr[A] = kp + __shfl_xor(snd, MASK, 64); }
        #pragma unroll
        for (int i = 0; i < 8; ++i) FOLD(1, i, i + 8)
        #pragma unroll
        for (int i = 0; i < 4; ++i) FOLD(2, i, i + 4)
        #pragma unroll
        for (int i = 0; i < 2; ++i) FOLD(4, i, i + 2)
        FOLD(8, 0, 1)
        #undef FOLD
        float val = pr[0] + __shfl_xor(pr[0], 16, 64);
        const int reff = ((lane & 1) << 3) | ((lane & 2) << 1) | ((lane & 4) >> 1) | ((lane & 8) >> 3);
        const int row  = (reff & 3) + ((reff >> 2) << 3) + grp * 4;
        if ((lane & 16) == 0) out[ebase + row] = val + b2v;
    }
}

extern "C" void kernel_launch(void* const* d_in, const int* in_sizes, int n_in,
                              void* d_out, int out_size, void* d_ws, size_t ws_size,
                              hipStream_t stream) {
    const float* h  = (const float*)d_in[0];
    const int*   ei = (const int*)d_in[1];
    const float* ea = (const float*)d_in[2];
    const float* W1 = (const float*)d_in[3];
    const float* b1 = (const float*)d_in[4];
    const float* W2 = (const float*)d_in[5];
    const float* b2 = (const float*)d_in[6];
    float* out = (float*)d_out;

    const size_t pre_bytes = (size_t)NNODES * 256;            // 12.8 MB
    const size_t s_bytes   = (size_t)NNODES * sizeof(float);  // 200 KB each
    const size_t need = pre_bytes + 2 * s_bytes;
    if (ws_size >= need) {
        unsigned char* pre8 = (unsigned char*)d_ws;
        float* sUp = (float*)((char*)d_ws + pre_bytes);
        float* sVp = (float*)((char*)d_ws + pre_bytes + s_bytes);
        const int mblocks = ((NNODES + 127) / 128) * 2;   // 782
        hipLaunchKernelGGL(gemm_pre, dim3(mblocks), dim3(256), 0, stream,
                           h, W1, b1, pre8, sUp, sVp);
        hipLaunchKernelGGL(edge_apply, dim3(NBLK), dim3(256), 0, stream,
                           pre8, sUp, sVp, ei, ea, W1, W2, b2, out);
    } else {
        hipLaunchKernelGGL(edgehead_mono, dim3(NWG), dim3(256), 0, stream,
                           h, ei, ea, W1, b1, W2, b2, out);
    }
}